// Round 4
// baseline (867.387 us; speedup 1.0000x reference)
//
#include <hip/hip_runtime.h>
#include <hip/hip_bf16.h>
#include <math.h>
#include <stdint.h>

#define NN 50000
#define NE 400000

typedef __attribute__((ext_vector_type(8))) short short8;
typedef __attribute__((ext_vector_type(4))) float f32x4;

// bf16 weight workspace layout (element offsets)
#define OFF_WE1T 0           // [128][320]
#define OFF_WE2T 40960       // [128][128]
#define OFF_WN1T 57344       // [128][256]
#define OFF_WN2T 90112       // [128][128]
#define OFF_WC1T 106496      // [64][128]
#define W_TOTAL  114688

__device__ __forceinline__ float silu_f(float x) {
    return x * (1.0f / (1.0f + __expf(-x)));
}
__device__ __forceinline__ short f2bf(float f) {
    __hip_bfloat16 b = __float2bfloat16(f);
    return *reinterpret_cast<short*>(&b);
}
__device__ __forceinline__ uint32_t pk2(float lo, float hi) {
    return (uint32_t)(uint16_t)f2bf(lo) | ((uint32_t)(uint16_t)f2bf(hi) << 16);
}
__device__ __forceinline__ short8 cvt8(float4 a, float4 b) {
    short8 r;
    r[0] = f2bf(a.x); r[1] = f2bf(a.y); r[2] = f2bf(a.z); r[3] = f2bf(a.w);
    r[4] = f2bf(b.x); r[5] = f2bf(b.y); r[6] = f2bf(b.z); r[7] = f2bf(b.w);
    return r;
}

// Build next-GEMM B-fragment (lane&15 = edge col, k'-slice g*8) from the
// producing C-fragment packs. e0/e1 = tile 2cc regs, o0/o1 = tile 2cc+1.
__device__ __forceinline__ short8 exch8(uint32_t e0, uint32_t e1,
                                        uint32_t o0, uint32_t o1,
                                        int g, int le) {
    const int srcA = le + 16 * ((g & 1) * 2);
    const int srcB = srcA + 16;
    const uint32_t a0e = __shfl((int)e0, srcA), a0o = __shfl((int)o0, srcA);
    const uint32_t a1e = __shfl((int)e1, srcA), a1o = __shfl((int)o1, srcA);
    const uint32_t b0e = __shfl((int)e0, srcB), b0o = __shfl((int)o0, srcB);
    const uint32_t b1e = __shfl((int)e1, srcB), b1o = __shfl((int)o1, srcB);
    const bool hi = (g & 2) != 0;
    uint32_t v[4];
    v[0] = hi ? a0o : a0e;  v[1] = hi ? a1o : a1e;
    v[2] = hi ? b0o : b0e;  v[3] = hi ? b1o : b1e;
    short8 r; __builtin_memcpy(&r, v, 16); return r;
}

// ---------------- zero aggr/coord accumulators ----------------
__global__ void zero_kernel(float4* __restrict__ p, int n4) {
    int i = blockIdx.x * blockDim.x + threadIdx.x;
    int st = gridDim.x * blockDim.x;
    for (; i < n4; i += st) p[i] = make_float4(0.f, 0.f, 0.f, 0.f);
}

// ---------------- weight prep: fp32 [K][N] -> bf16 transposed [N][K] ----------------
__global__ __launch_bounds__(256) void prep_kernel(
    const float* __restrict__ We1, const float* __restrict__ We2,
    const float* __restrict__ Wn1, const float* __restrict__ Wn2,
    const float* __restrict__ Wc1, short* __restrict__ wb)
{
    const int i = blockIdx.x * 256 + threadIdx.x;
    const float* src; int N, n, k, rel;
    if (i < OFF_WE2T)      { rel = i;            src = We1; N = 128; n = rel / 320; k = rel % 320; }
    else if (i < OFF_WN1T) { rel = i - OFF_WE2T; src = We2; N = 128; n = rel / 128; k = rel % 128; }
    else if (i < OFF_WN2T) { rel = i - OFF_WN1T; src = Wn1; N = 128; n = rel / 256; k = rel % 256; }
    else if (i < OFF_WC1T) { rel = i - OFF_WN2T; src = Wn2; N = 128; n = rel / 128; k = rel % 128; }
    else                   { rel = i - OFF_WC1T; src = Wc1; N = 64;  n = rel / 128; k = rel % 128; }
    wb[i] = f2bf(src[(size_t)k * N + n]);
}

// ---------------- node_feat fp32 -> bf16 ----------------
__global__ __launch_bounds__(256) void nf2bf_kernel(
    const float* __restrict__ nf, short* __restrict__ nfb)
{
    const int n8 = NN * 128 / 8;
    int i = blockIdx.x * blockDim.x + threadIdx.x;
    const int st = gridDim.x * blockDim.x;
    for (; i < n8; i += st) {
        const float4 a = *(const float4*)&nf[(size_t)i * 8];
        const float4 b = *(const float4*)&nf[(size_t)i * 8 + 4];
        *(short8*)&nfb[(size_t)i * 8] = cvt8(a, b);
    }
}

// ---------------- edge pipeline: persistent blocks, weights in LDS ----------------
// 256 blocks x 768 threads (12 waves). Weights staged to LDS once (136 KB).
// Each wave processes 32-edge tiles independently (no barriers in the loop).
// All GEMMs swapped (h^T = W^T x^T): C-frag col = edge, so next-GEMM operands
// are rebuilt in-register via shfl exchange (no H in LDS).
template<bool BF16NF>
__global__ __launch_bounds__(768, 3) void edge_kernel(
    const float* __restrict__ nf, const short* __restrict__ nfb,
    const float* __restrict__ ea,
    const float* __restrict__ coords, const int* __restrict__ ei,
    const short* __restrict__ wb,
    const float* __restrict__ be1, const float* __restrict__ be2,
    const float* __restrict__ bc1, const float* __restrict__ bc2,
    const float* __restrict__ Wc2f,
    float* __restrict__ aggr, float* __restrict__ coord_acc)
{
    __shared__ __align__(16) short W1s[128 * 328];  // pad 320->328: bank-spread b128
    __shared__ __align__(16) short W2s[128 * 136];
    __shared__ __align__(16) short Wcs[64 * 136];

    const int tid = threadIdx.x;
    for (int i = tid; i < 5120; i += 768) {         // We1: 128 x 320
        const int n = i / 40, k = (i % 40) * 8;
        *(short8*)&W1s[n * 328 + k] = *(const short8*)&wb[OFF_WE1T + n * 320 + k];
    }
    for (int i = tid; i < 2048; i += 768) {         // We2: 128 x 128
        const int n = i >> 4, k = (i & 15) * 8;
        *(short8*)&W2s[n * 136 + k] = *(const short8*)&wb[OFF_WE2T + n * 128 + k];
    }
    for (int i = tid; i < 1024; i += 768) {         // Wc1: 64 x 128
        const int n = i >> 4, k = (i & 15) * 8;
        *(short8*)&Wcs[n * 136 + k] = *(const short8*)&wb[OFF_WC1T + n * 128 + k];
    }
    __syncthreads();

    const int wv = tid >> 6, lane = tid & 63, le = lane & 15, g = lane >> 4;

    for (int tile = blockIdx.x * 12 + wv; tile < NE / 32; tile += 256 * 12) {
        const int base = tile * 32;
        const int s0 = ei[base + le],      s1 = ei[base + 16 + le];
        const int d0 = ei[NE + base + le], d1 = ei[NE + base + 16 + le];

        // ===== MLP1 (swapped): acc[m][t] holds h1[e=le+16m][n=t*16+g*4+r]
        f32x4 acc[2][8];
        #pragma unroll
        for (int m = 0; m < 2; ++m)
            #pragma unroll
            for (int t = 0; t < 8; ++t) acc[m][t] = (f32x4){0.f, 0.f, 0.f, 0.f};

        #pragma unroll
        for (int kc = 0; kc < 10; ++kc) {
            const int gk = kc * 32 + g * 8;
            short8 a0, a1;
            if (kc < 8) {
                const int r0 = (kc < 4) ? s0 : d0;
                const int r1 = (kc < 4) ? s1 : d1;
                const int off = gk & 127;
                if (BF16NF) {
                    a0 = *(const short8*)&nfb[(size_t)r0 * 128 + off];
                    a1 = *(const short8*)&nfb[(size_t)r1 * 128 + off];
                } else {
                    const float* p0 = nf + (size_t)r0 * 128 + off;
                    const float* p1 = nf + (size_t)r1 * 128 + off;
                    a0 = cvt8(*(const float4*)p0, *(const float4*)(p0 + 4));
                    a1 = cvt8(*(const float4*)p1, *(const float4*)(p1 + 4));
                }
            } else {
                const float* p0 = ea + (size_t)(base + le) * 64 + gk - 256;
                const float* p1 = ea + (size_t)(base + 16 + le) * 64 + gk - 256;
                a0 = cvt8(*(const float4*)p0, *(const float4*)(p0 + 4));
                a1 = cvt8(*(const float4*)p1, *(const float4*)(p1 + 4));
            }
            #pragma unroll
            for (int t = 0; t < 8; ++t) {
                const short8 wf = *(const short8*)&W1s[(t * 16 + le) * 328 + gk];
                acc[0][t] = __builtin_amdgcn_mfma_f32_16x16x32_bf16(wf, a0, acc[0][t], 0, 0, 0);
                acc[1][t] = __builtin_amdgcn_mfma_f32_16x16x32_bf16(wf, a1, acc[1][t], 0, 0, 0);
            }
        }

        // bias + silu + pack h1 to bf16 pairs
        uint32_t hp[2][8][2];
        #pragma unroll
        for (int t = 0; t < 8; ++t) {
            const float4 b = *(const float4*)&be1[t * 16 + g * 4];
            #pragma unroll
            for (int m = 0; m < 2; ++m) {
                const float x0 = silu_f(acc[m][t][0] + b.x);
                const float x1 = silu_f(acc[m][t][1] + b.y);
                const float x2 = silu_f(acc[m][t][2] + b.z);
                const float x3 = silu_f(acc[m][t][3] + b.w);
                hp[m][t][0] = pk2(x0, x1);
                hp[m][t][1] = pk2(x2, x3);
            }
        }

        // ===== MLP2 (swapped), K'=128
        f32x4 acc2[2][8];
        #pragma unroll
        for (int m = 0; m < 2; ++m)
            #pragma unroll
            for (int t = 0; t < 8; ++t) acc2[m][t] = (f32x4){0.f, 0.f, 0.f, 0.f};

        #pragma unroll
        for (int cc = 0; cc < 4; ++cc) {
            const int gk = cc * 32 + g * 8;
            const short8 x0 = exch8(hp[0][cc*2][0], hp[0][cc*2][1], hp[0][cc*2+1][0], hp[0][cc*2+1][1], g, le);
            const short8 x1 = exch8(hp[1][cc*2][0], hp[1][cc*2][1], hp[1][cc*2+1][0], hp[1][cc*2+1][1], g, le);
            #pragma unroll
            for (int t = 0; t < 8; ++t) {
                const short8 wf = *(const short8*)&W2s[(t * 16 + le) * 136 + gk];
                acc2[0][t] = __builtin_amdgcn_mfma_f32_16x16x32_bf16(wf, x0, acc2[0][t], 0, 0, 0);
                acc2[1][t] = __builtin_amdgcn_mfma_f32_16x16x32_bf16(wf, x1, acc2[1][t], 0, 0, 0);
            }
        }

        // bias + silu + atomic scatter + pack h2
        #pragma unroll
        for (int t = 0; t < 8; ++t) {
            const float4 b = *(const float4*)&be2[t * 16 + g * 4];
            #pragma unroll
            for (int m = 0; m < 2; ++m) {
                const int dst = m ? d1 : d0;
                float* abase = aggr + (size_t)dst * 128 + t * 16 + g * 4;
                const float x0 = silu_f(acc2[m][t][0] + b.x);
                const float x1 = silu_f(acc2[m][t][1] + b.y);
                const float x2 = silu_f(acc2[m][t][2] + b.z);
                const float x3 = silu_f(acc2[m][t][3] + b.w);
                atomicAdd(abase + 0, x0);
                atomicAdd(abase + 1, x1);
                atomicAdd(abase + 2, x2);
                atomicAdd(abase + 3, x3);
                hp[m][t][0] = pk2(x0, x1);
                hp[m][t][1] = pk2(x2, x3);
            }
        }

        // ===== coord MLP (swapped), N=64
        f32x4 acc3[2][4];
        #pragma unroll
        for (int m = 0; m < 2; ++m)
            #pragma unroll
            for (int t = 0; t < 4; ++t) acc3[m][t] = (f32x4){0.f, 0.f, 0.f, 0.f};

        #pragma unroll
        for (int cc = 0; cc < 4; ++cc) {
            const int gk = cc * 32 + g * 8;
            const short8 x0 = exch8(hp[0][cc*2][0], hp[0][cc*2][1], hp[0][cc*2+1][0], hp[0][cc*2+1][1], g, le);
            const short8 x1 = exch8(hp[1][cc*2][0], hp[1][cc*2][1], hp[1][cc*2+1][0], hp[1][cc*2+1][1], g, le);
            #pragma unroll
            for (int t = 0; t < 4; ++t) {
                const short8 wf = *(const short8*)&Wcs[(t * 16 + le) * 136 + gk];
                acc3[0][t] = __builtin_amdgcn_mfma_f32_16x16x32_bf16(wf, x0, acc3[0][t], 0, 0, 0);
                acc3[1][t] = __builtin_amdgcn_mfma_f32_16x16x32_bf16(wf, x1, acc3[1][t], 0, 0, 0);
            }
        }

        // coord_w: per-lane partial over 16 cols, butterfly over g (lanes +-16, +-32)
        float part0 = 0.f, part1 = 0.f;
        #pragma unroll
        for (int t = 0; t < 4; ++t) {
            const float4 bc = *(const float4*)&bc1[t * 16 + g * 4];
            const float4 wc = *(const float4*)&Wc2f[t * 16 + g * 4];
            part0 += silu_f(acc3[0][t][0] + bc.x) * wc.x + silu_f(acc3[0][t][1] + bc.y) * wc.y
                   + silu_f(acc3[0][t][2] + bc.z) * wc.z + silu_f(acc3[0][t][3] + bc.w) * wc.w;
            part1 += silu_f(acc3[1][t][0] + bc.x) * wc.x + silu_f(acc3[1][t][1] + bc.y) * wc.y
                   + silu_f(acc3[1][t][2] + bc.z) * wc.z + silu_f(acc3[1][t][3] + bc.w) * wc.w;
        }
        part0 += __shfl_xor(part0, 16); part0 += __shfl_xor(part0, 32);
        part1 += __shfl_xor(part1, 16); part1 += __shfl_xor(part1, 32);

        // geometry + coord scatter: g==0 handles edge le, g==1 handles edge le+16
        if (g < 2) {
            const int s = g ? s1 : s0, d = g ? d1 : d0;
            const float wq = (g ? part1 : part0) + bc2[0];
            const float dx = coords[3 * s + 0] - coords[3 * d + 0];
            const float dy = coords[3 * s + 1] - coords[3 * d + 1];
            const float dz = coords[3 * s + 2] - coords[3 * d + 2];
            const float inv = wq / (sqrtf(dx * dx + dy * dy + dz * dz) + 1e-8f);
            atomicAdd(&coord_acc[3 * d + 0], dx * inv);
            atomicAdd(&coord_acc[3 * d + 1], dy * inv);
            atomicAdd(&coord_acc[3 * d + 2], dz * inv);
        }
    }
}

// ---------------- node update (MFMA, barrier-free) ----------------
__global__ __launch_bounds__(256, 4) void node_kernel(
    const float* __restrict__ nf, const float* __restrict__ coords,
    const short* __restrict__ wb,
    const float* __restrict__ bn1, const float* __restrict__ bn2,
    const float* __restrict__ aggr, const float* __restrict__ coord_acc,
    float* __restrict__ out)
{
    __shared__ short Hs[128][136];

    const int tid   = threadIdx.x;
    const int wv    = tid >> 6;
    const int lane  = tid & 63;
    const int le    = lane & 15;
    const int grp   = lane >> 4;
    const int nb    = blockIdx.x * 128;
    const int wbase = wv * 32;

    const int row0 = min(nb + wbase + le, NN - 1);
    const int row1 = min(nb + wbase + 16 + le, NN - 1);

    f32x4 acc[2][8];
    #pragma unroll
    for (int m = 0; m < 2; ++m)
        #pragma unroll
        for (int t = 0; t < 8; ++t) acc[m][t] = (f32x4){0.f, 0.f, 0.f, 0.f};

    const short* w1 = wb + OFF_WN1T;
    #pragma unroll
    for (int kc = 0; kc < 8; ++kc) {
        const int gk = kc * 32 + grp * 8;
        const float* p0 = (kc < 4) ? nf + (size_t)row0 * 128 + gk : aggr + (size_t)row0 * 128 + gk - 128;
        const float* p1 = (kc < 4) ? nf + (size_t)row1 * 128 + gk : aggr + (size_t)row1 * 128 + gk - 128;
        const short8 a0 = cvt8(*(const float4*)p0, *(const float4*)(p0 + 4));
        const short8 a1 = cvt8(*(const float4*)p1, *(const float4*)(p1 + 4));
        #pragma unroll
        for (int th = 0; th < 2; ++th) {
            short8 bf[4];
            #pragma unroll
            for (int t4 = 0; t4 < 4; ++t4)
                bf[t4] = *(const short8*)(w1 + (size_t)((th * 4 + t4) * 16 + le) * 256 + gk);
            #pragma unroll
            for (int t4 = 0; t4 < 4; ++t4) {
                acc[0][th*4+t4] = __builtin_amdgcn_mfma_f32_16x16x32_bf16(a0, bf[t4], acc[0][th*4+t4], 0, 0, 0);
                acc[1][th*4+t4] = __builtin_amdgcn_mfma_f32_16x16x32_bf16(a1, bf[t4], acc[1][th*4+t4], 0, 0, 0);
            }
        }
    }
    #pragma unroll
    for (int t = 0; t < 8; ++t) {
        const float b1 = bn1[t * 16 + le];
        #pragma unroll
        for (int m = 0; m < 2; ++m)
            #pragma unroll
            for (int r = 0; r < 4; ++r)
                Hs[wbase + m * 16 + grp * 4 + r][t * 16 + le] = f2bf(silu_f(acc[m][t][r] + b1));
    }

    f32x4 acc2[2][8];
    #pragma unroll
    for (int m = 0; m < 2; ++m)
        #pragma unroll
        for (int t = 0; t < 8; ++t) acc2[m][t] = (f32x4){0.f, 0.f, 0.f, 0.f};

    const short* w2 = wb + OFF_WN2T;
    #pragma unroll
    for (int kc = 0; kc < 4; ++kc) {
        const int gk = kc * 32 + grp * 8;
        const short8 a0 = *(const short8*)&Hs[wbase + le][gk];
        const short8 a1 = *(const short8*)&Hs[wbase + 16 + le][gk];
        #pragma unroll
        for (int th = 0; th < 2; ++th) {
            short8 bf[4];
            #pragma unroll
            for (int t4 = 0; t4 < 4; ++t4)
                bf[t4] = *(const short8*)(w2 + (size_t)((th * 4 + t4) * 16 + le) * 128 + gk);
            #pragma unroll
            for (int t4 = 0; t4 < 4; ++t4) {
                acc2[0][th*4+t4] = __builtin_amdgcn_mfma_f32_16x16x32_bf16(a0, bf[t4], acc2[0][th*4+t4], 0, 0, 0);
                acc2[1][th*4+t4] = __builtin_amdgcn_mfma_f32_16x16x32_bf16(a1, bf[t4], acc2[1][th*4+t4], 0, 0, 0);
            }
        }
    }
    #pragma unroll
    for (int t = 0; t < 8; ++t) {
        const float b2 = bn2[t * 16 + le];
        #pragma unroll
        for (int m = 0; m < 2; ++m)
            #pragma unroll
            for (int r = 0; r < 4; ++r) {
                const int row = nb + wbase + m * 16 + grp * 4 + r;
                if (row < NN) {
                    const int c = t * 16 + le;
                    out[(size_t)row * 128 + c] = acc2[m][t][r] + b2 + nf[(size_t)row * 128 + c];
                }
            }
    }

    for (int i = tid; i < 384; i += 256) {
        const int n = nb + i / 3, j = i % 3;
        if (n < NN)
            out[(size_t)NN * 128 + 3 * n + j] = coords[3 * n + j] + coord_acc[3 * n + j];
    }
}

extern "C" void kernel_launch(void* const* d_in, const int* in_sizes, int n_in,
                              void* d_out, int out_size, void* d_ws, size_t ws_size,
                              hipStream_t stream)
{
    const float* node_feat  = (const float*)d_in[0];
    const float* edge_attr  = (const float*)d_in[1];
    const float* coords     = (const float*)d_in[2];
    const int*   edge_index = (const int*)d_in[3];
    const float* We1 = (const float*)d_in[4];
    const float* be1 = (const float*)d_in[5];
    const float* We2 = (const float*)d_in[6];
    const float* be2 = (const float*)d_in[7];
    const float* Wn1 = (const float*)d_in[8];
    const float* bn1 = (const float*)d_in[9];
    const float* Wn2 = (const float*)d_in[10];
    const float* bn2 = (const float*)d_in[11];
    const float* Wc1 = (const float*)d_in[12];
    const float* bc1 = (const float*)d_in[13];
    const float* Wc2 = (const float*)d_in[14];
    const float* bc2 = (const float*)d_in[15];

    float* out       = (float*)d_out;
    float* aggr      = (float*)d_ws;                          // [NN,128] f32
    float* coord_acc = aggr + (size_t)NN * 128;               // [NN,3]   f32
    short* wbf       = (short*)(coord_acc + (size_t)NN * 3);  // bf16 weights
    short* nfb       = wbf + W_TOTAL;                         // bf16 node_feat

    const size_t need = ((size_t)NN * 128 + (size_t)NN * 3) * 4
                      + ((size_t)W_TOTAL + (size_t)NN * 128) * 2;
    const bool use_bf = ws_size >= need;

    prep_kernel<<<W_TOTAL / 256, 256, 0, stream>>>(We1, We2, Wn1, Wn2, Wc1, wbf);
    if (use_bf)
        nf2bf_kernel<<<2048, 256, 0, stream>>>(node_feat, nfb);

    const int n4 = (NN * 128 + NN * 3) / 4;   // re-zero accumulators every call
    zero_kernel<<<2048, 256, 0, stream>>>((float4*)d_ws, n4);

    if (use_bf)
        edge_kernel<true><<<256, 768, 0, stream>>>(
            node_feat, nfb, edge_attr, coords, edge_index, wbf,
            be1, be2, bc1, bc2, Wc2, aggr, coord_acc);
    else
        edge_kernel<false><<<256, 768, 0, stream>>>(
            node_feat, nfb, edge_attr, coords, edge_index, wbf,
            be1, be2, bc1, bc2, Wc2, aggr, coord_acc);

    node_kernel<<<(NN + 127) / 128, 256, 0, stream>>>(
        node_feat, coords, wbf, bn1, bn2, aggr, coord_acc, out);
}

// Round 5
// 518.070 us; speedup vs baseline: 1.6743x; 1.6743x over previous
//
#include <hip/hip_runtime.h>
#include <hip/hip_bf16.h>
#include <math.h>
#include <stdint.h>

#define NN 50000
#define NE 400000

typedef __attribute__((ext_vector_type(8))) short short8;
typedef __attribute__((ext_vector_type(4))) float f32x4;

// bf16 weight workspace layout (element offsets)
#define OFF_WE1T 0           // [128][320]
#define OFF_WE2T 40960       // [128][128]
#define OFF_WN1T 57344       // [128][256]
#define OFF_WN2T 90112       // [128][128]
#define OFF_WC1T 106496      // [64][128]
#define W_TOTAL  114688

#define NFB_ITEMS 800000     // NN*128/8

__device__ __forceinline__ float silu_f(float x) {
    return x * (1.0f / (1.0f + __expf(-x)));
}
__device__ __forceinline__ short f2bf(float f) {
    __hip_bfloat16 b = __float2bfloat16(f);
    return *reinterpret_cast<short*>(&b);
}
__device__ __forceinline__ float bf2f(short s) {
    uint32_t u = ((uint32_t)(uint16_t)s) << 16;
    float f; __builtin_memcpy(&f, &u, 4); return f;
}
__device__ __forceinline__ uint32_t pk2(float lo, float hi) {
    return (uint32_t)(uint16_t)f2bf(lo) | ((uint32_t)(uint16_t)f2bf(hi) << 16);
}
__device__ __forceinline__ short8 cvt8(float4 a, float4 b) {
    short8 r;
    r[0] = f2bf(a.x); r[1] = f2bf(a.y); r[2] = f2bf(a.z); r[3] = f2bf(a.w);
    r[4] = f2bf(b.x); r[5] = f2bf(b.y); r[6] = f2bf(b.z); r[7] = f2bf(b.w);
    return r;
}

// Build next-GEMM B-fragment (lane&15 = edge col, k'-slice g*8) from the
// producing C-fragment packs. Proven correct in round 3->4.
__device__ __forceinline__ short8 exch8(uint32_t e0, uint32_t e1,
                                        uint32_t o0, uint32_t o1,
                                        int g, int le) {
    const int srcA = le + 16 * ((g & 1) * 2);
    const int srcB = srcA + 16;
    const uint32_t a0e = __shfl((int)e0, srcA), a0o = __shfl((int)o0, srcA);
    const uint32_t a1e = __shfl((int)e1, srcA), a1o = __shfl((int)o1, srcA);
    const uint32_t b0e = __shfl((int)e0, srcB), b0o = __shfl((int)o0, srcB);
    const uint32_t b1e = __shfl((int)e1, srcB), b1o = __shfl((int)o1, srcB);
    const bool hi = (g & 2) != 0;
    uint32_t v[4];
    v[0] = hi ? a0o : a0e;  v[1] = hi ? a1o : a1e;
    v[2] = hi ? b0o : b0e;  v[3] = hi ? b1o : b1e;
    short8 r; __builtin_memcpy(&r, v, 16); return r;
}

// ---------------- zero (fallback accumulators) ----------------
__global__ void zero_kernel(float4* __restrict__ p, int n4) {
    int i = blockIdx.x * blockDim.x + threadIdx.x;
    int st = gridDim.x * blockDim.x;
    for (; i < n4; i += st) p[i] = make_float4(0.f, 0.f, 0.f, 0.f);
}

// ---------------- prep: weights transpose->bf16, nf->bf16, cnt zero ----------------
__global__ __launch_bounds__(256) void prep_all_kernel(
    const float* __restrict__ We1, const float* __restrict__ We2,
    const float* __restrict__ Wn1, const float* __restrict__ Wn2,
    const float* __restrict__ Wc1, const float* __restrict__ nf,
    short* __restrict__ wb, short* __restrict__ nfb, int* __restrict__ cnt,
    int do_nfb, int do_cnt)
{
    const int i = blockIdx.x * 256 + threadIdx.x;
    if (i < W_TOTAL) {
        const float* src; int N, n, k, rel;
        if (i < OFF_WE2T)      { rel = i;            src = We1; N = 128; n = rel / 320; k = rel % 320; }
        else if (i < OFF_WN1T) { rel = i - OFF_WE2T; src = We2; N = 128; n = rel / 128; k = rel % 128; }
        else if (i < OFF_WN2T) { rel = i - OFF_WN1T; src = Wn1; N = 128; n = rel / 256; k = rel % 256; }
        else if (i < OFF_WC1T) { rel = i - OFF_WN2T; src = Wn2; N = 128; n = rel / 128; k = rel % 128; }
        else                   { rel = i - OFF_WC1T; src = Wc1; N = 64;  n = rel / 128; k = rel % 128; }
        wb[i] = f2bf(src[(size_t)k * N + n]);
    } else if (i < W_TOTAL + NFB_ITEMS) {
        if (do_nfb) {
            const int j = i - W_TOTAL;
            const float4 a = *(const float4*)&nf[(size_t)j * 8];
            const float4 b = *(const float4*)&nf[(size_t)j * 8 + 4];
            *(short8*)&nfb[(size_t)j * 8] = cvt8(a, b);
        }
    } else if (i < W_TOTAL + NFB_ITEMS + NN) {
        if (do_cnt) cnt[i - W_TOTAL - NFB_ITEMS] = 0;
    }
}

// ---------------- CSR build ----------------
__global__ __launch_bounds__(256) void hist_kernel(const int* __restrict__ ei, int* __restrict__ cnt) {
    const int e = blockIdx.x * 256 + threadIdx.x;
    if (e < NE) atomicAdd(&cnt[ei[NE + e]], 1);
}

__global__ __launch_bounds__(256) void scanA_kernel(const int* __restrict__ cnt,
                                                    int* __restrict__ eoff, int* __restrict__ bsum) {
    __shared__ int sm[256];
    const int t = threadIdx.x, idx = blockIdx.x * 256 + t;
    const int v = (idx < NN) ? cnt[idx] : 0;
    sm[t] = v; __syncthreads();
    #pragma unroll
    for (int o = 1; o < 256; o <<= 1) {
        const int x = (t >= o) ? sm[t - o] : 0;
        __syncthreads();
        sm[t] += x;
        __syncthreads();
    }
    if (idx < NN) eoff[idx] = sm[t] - v;
    if (t == 255) bsum[blockIdx.x] = sm[255];
}

__global__ __launch_bounds__(256) void scanB_kernel(const int* __restrict__ bsum,
                                                    int* __restrict__ bexcl, int nb) {
    __shared__ int sm[256];
    const int t = threadIdx.x;
    const int v = (t < nb) ? bsum[t] : 0;
    sm[t] = v; __syncthreads();
    #pragma unroll
    for (int o = 1; o < 256; o <<= 1) {
        const int x = (t >= o) ? sm[t - o] : 0;
        __syncthreads();
        sm[t] += x;
        __syncthreads();
    }
    bexcl[t] = sm[t] - v;
}

__global__ __launch_bounds__(256) void scanC_kernel(const int* __restrict__ eoff,
                                                    const int* __restrict__ bexcl,
                                                    int* __restrict__ off, int* __restrict__ cursor) {
    const int idx = blockIdx.x * 256 + threadIdx.x;
    if (idx < NN) {
        const int o = eoff[idx] + bexcl[blockIdx.x];
        off[idx] = o;
        cursor[idx] = o;
    }
    if (idx == 0) off[NN] = NE;
}

__global__ __launch_bounds__(256) void fill_kernel(const int* __restrict__ ei,
                                                   int* __restrict__ cursor, int* __restrict__ csr) {
    const int e = blockIdx.x * 256 + threadIdx.x;
    if (e < NE) {
        const int pos = atomicAdd(&cursor[ei[NE + e]], 1);
        csr[pos] = e;
    }
}

// ---------------- pass A: edge pipeline (MFMA, barrier-free, no LDS) ----------------
// 128 edges/block, 4 waves, 32 edges/wave. Swapped GEMMs + register exchange.
// CSR mode: streams h2 (bf16) + coord_w; no atomics. Fallback: atomic scatter.
template<bool CSR, bool BF16NF>
__global__ __launch_bounds__(256, 4) void edge_kernel(
    const float* __restrict__ nf, const short* __restrict__ nfb,
    const float* __restrict__ ea, const float* __restrict__ coords,
    const int* __restrict__ ei, const short* __restrict__ wb,
    const float* __restrict__ be1, const float* __restrict__ be2,
    const float* __restrict__ bc1, const float* __restrict__ bc2,
    const float* __restrict__ Wc2f,
    short* __restrict__ h2, float* __restrict__ cw,
    float* __restrict__ aggr, float* __restrict__ coord_acc)
{
    const int tid = threadIdx.x;
    const int wv = tid >> 6, lane = tid & 63, le = lane & 15, g = lane >> 4;
    const int base = (blockIdx.x * 4 + wv) * 32;

    const int s0 = ei[base + le],      s1 = ei[base + 16 + le];
    const int d0 = ei[NE + base + le], d1 = ei[NE + base + 16 + le];

    // ===== MLP1 (swapped): acc[m][t] = h1[edge le+16m][n = t*16+g*4+r]
    f32x4 acc[2][8];
    #pragma unroll
    for (int m = 0; m < 2; ++m)
        #pragma unroll
        for (int t = 0; t < 8; ++t) acc[m][t] = (f32x4){0.f, 0.f, 0.f, 0.f};

    const short* w1 = wb + OFF_WE1T;
    #pragma unroll
    for (int kc = 0; kc < 10; ++kc) {
        const int gk = kc * 32 + g * 8;
        short8 a0, a1;
        if (kc < 8) {
            const int r0 = (kc < 4) ? s0 : d0;
            const int r1 = (kc < 4) ? s1 : d1;
            const int o = gk & 127;
            if (BF16NF) {
                a0 = *(const short8*)&nfb[(size_t)r0 * 128 + o];
                a1 = *(const short8*)&nfb[(size_t)r1 * 128 + o];
            } else {
                const float* p0 = nf + (size_t)r0 * 128 + o;
                const float* p1 = nf + (size_t)r1 * 128 + o;
                a0 = cvt8(*(const float4*)p0, *(const float4*)(p0 + 4));
                a1 = cvt8(*(const float4*)p1, *(const float4*)(p1 + 4));
            }
        } else {
            const float* p0 = ea + (size_t)(base + le) * 64 + gk - 256;
            const float* p1 = ea + (size_t)(base + 16 + le) * 64 + gk - 256;
            a0 = cvt8(*(const float4*)p0, *(const float4*)(p0 + 4));
            a1 = cvt8(*(const float4*)p1, *(const float4*)(p1 + 4));
        }
        short8 wfv[8];
        #pragma unroll
        for (int t = 0; t < 8; ++t)
            wfv[t] = *(const short8*)(w1 + (size_t)(t * 16 + le) * 320 + gk);
        #pragma unroll
        for (int t = 0; t < 8; ++t) {
            acc[0][t] = __builtin_amdgcn_mfma_f32_16x16x32_bf16(wfv[t], a0, acc[0][t], 0, 0, 0);
            acc[1][t] = __builtin_amdgcn_mfma_f32_16x16x32_bf16(wfv[t], a1, acc[1][t], 0, 0, 0);
        }
    }

    // bias + silu + pack h1
    uint32_t hp[2][8][2];
    #pragma unroll
    for (int t = 0; t < 8; ++t) {
        const float4 b = *(const float4*)&be1[t * 16 + g * 4];
        #pragma unroll
        for (int m = 0; m < 2; ++m) {
            const float x0 = silu_f(acc[m][t][0] + b.x);
            const float x1 = silu_f(acc[m][t][1] + b.y);
            const float x2 = silu_f(acc[m][t][2] + b.z);
            const float x3 = silu_f(acc[m][t][3] + b.w);
            hp[m][t][0] = pk2(x0, x1);
            hp[m][t][1] = pk2(x2, x3);
        }
    }

    // ===== MLP2 (swapped), K'=128
    f32x4 acc2[2][8];
    #pragma unroll
    for (int m = 0; m < 2; ++m)
        #pragma unroll
        for (int t = 0; t < 8; ++t) acc2[m][t] = (f32x4){0.f, 0.f, 0.f, 0.f};

    const short* w2 = wb + OFF_WE2T;
    #pragma unroll
    for (int cc = 0; cc < 4; ++cc) {
        const int gk = cc * 32 + g * 8;
        const short8 x0 = exch8(hp[0][cc*2][0], hp[0][cc*2][1], hp[0][cc*2+1][0], hp[0][cc*2+1][1], g, le);
        const short8 x1 = exch8(hp[1][cc*2][0], hp[1][cc*2][1], hp[1][cc*2+1][0], hp[1][cc*2+1][1], g, le);
        short8 wfv[8];
        #pragma unroll
        for (int t = 0; t < 8; ++t)
            wfv[t] = *(const short8*)(w2 + (size_t)(t * 16 + le) * 128 + gk);
        #pragma unroll
        for (int t = 0; t < 8; ++t) {
            acc2[0][t] = __builtin_amdgcn_mfma_f32_16x16x32_bf16(wfv[t], x0, acc2[0][t], 0, 0, 0);
            acc2[1][t] = __builtin_amdgcn_mfma_f32_16x16x32_bf16(wfv[t], x1, acc2[1][t], 0, 0, 0);
        }
    }

    // bias + silu + pack h2
    #pragma unroll
    for (int t = 0; t < 8; ++t) {
        const float4 b = *(const float4*)&be2[t * 16 + g * 4];
        #pragma unroll
        for (int m = 0; m < 2; ++m) {
            const float x0 = silu_f(acc2[m][t][0] + b.x);
            const float x1 = silu_f(acc2[m][t][1] + b.y);
            const float x2 = silu_f(acc2[m][t][2] + b.z);
            const float x3 = silu_f(acc2[m][t][3] + b.w);
            hp[m][t][0] = pk2(x0, x1);
            hp[m][t][1] = pk2(x2, x3);
        }
    }

    // ===== coord MLP (swapped, N=64) + h2 store / atomic scatter fused per cc
    f32x4 acc3[2][4];
    #pragma unroll
    for (int m = 0; m < 2; ++m)
        #pragma unroll
        for (int t = 0; t < 4; ++t) acc3[m][t] = (f32x4){0.f, 0.f, 0.f, 0.f};

    const short* wc = wb + OFF_WC1T;
    #pragma unroll
    for (int cc = 0; cc < 4; ++cc) {
        const int gk = cc * 32 + g * 8;
        const short8 x0 = exch8(hp[0][cc*2][0], hp[0][cc*2][1], hp[0][cc*2+1][0], hp[0][cc*2+1][1], g, le);
        const short8 x1 = exch8(hp[1][cc*2][0], hp[1][cc*2][1], hp[1][cc*2+1][0], hp[1][cc*2+1][1], g, le);
        if constexpr (CSR) {
            // lane holds edge (base+le[+16])'s cols gk..gk+7 -> coalesced row stream
            *(short8*)&h2[(size_t)(base + le) * 128 + gk]      = x0;
            *(short8*)&h2[(size_t)(base + 16 + le) * 128 + gk] = x1;
        } else {
            #pragma unroll
            for (int j = 0; j < 8; ++j) {
                atomicAdd(&aggr[(size_t)d0 * 128 + gk + j], bf2f(x0[j]));
                atomicAdd(&aggr[(size_t)d1 * 128 + gk + j], bf2f(x1[j]));
            }
        }
        short8 wfv[4];
        #pragma unroll
        for (int t = 0; t < 4; ++t)
            wfv[t] = *(const short8*)(wc + (size_t)(t * 16 + le) * 128 + gk);
        #pragma unroll
        for (int t = 0; t < 4; ++t) {
            acc3[0][t] = __builtin_amdgcn_mfma_f32_16x16x32_bf16(wfv[t], x0, acc3[0][t], 0, 0, 0);
            acc3[1][t] = __builtin_amdgcn_mfma_f32_16x16x32_bf16(wfv[t], x1, acc3[1][t], 0, 0, 0);
        }
    }

    // coord_w: per-lane partial, butterfly over g (lanes +-16, +-32)
    float part0 = 0.f, part1 = 0.f;
    #pragma unroll
    for (int t = 0; t < 4; ++t) {
        const float4 bc = *(const float4*)&bc1[t * 16 + g * 4];
        const float4 wcv = *(const float4*)&Wc2f[t * 16 + g * 4];
        part0 += silu_f(acc3[0][t][0] + bc.x) * wcv.x + silu_f(acc3[0][t][1] + bc.y) * wcv.y
               + silu_f(acc3[0][t][2] + bc.z) * wcv.z + silu_f(acc3[0][t][3] + bc.w) * wcv.w;
        part1 += silu_f(acc3[1][t][0] + bc.x) * wcv.x + silu_f(acc3[1][t][1] + bc.y) * wcv.y
               + silu_f(acc3[1][t][2] + bc.z) * wcv.z + silu_f(acc3[1][t][3] + bc.w) * wcv.w;
    }
    part0 += __shfl_xor(part0, 16); part0 += __shfl_xor(part0, 32);
    part1 += __shfl_xor(part1, 16); part1 += __shfl_xor(part1, 32);

    if (g < 2) {
        const float wq = (g ? part1 : part0) + bc2[0];
        const int eidx = base + (g ? 16 : 0) + le;
        if constexpr (CSR) {
            cw[eidx] = wq;
        } else {
            const int s = g ? s1 : s0, d = g ? d1 : d0;
            const float dx = coords[3 * s + 0] - coords[3 * d + 0];
            const float dy = coords[3 * s + 1] - coords[3 * d + 1];
            const float dz = coords[3 * s + 2] - coords[3 * d + 2];
            const float inv = wq / (sqrtf(dx * dx + dy * dy + dz * dz) + 1e-8f);
            atomicAdd(&coord_acc[3 * d + 0], dx * inv);
            atomicAdd(&coord_acc[3 * d + 1], dy * inv);
            atomicAdd(&coord_acc[3 * d + 2], dz * inv);
        }
    }
}

// ---------------- pass B: node update (MFMA + CSR gather-sum) ----------------
template<bool CSR, bool BF16NF>
__global__ __launch_bounds__(256, 2) void node_kernel(
    const float* __restrict__ nf, const short* __restrict__ nfb,
    const float* __restrict__ coords, const short* __restrict__ wb,
    const float* __restrict__ bn1, const float* __restrict__ bn2,
    const float* __restrict__ aggr, const float* __restrict__ coord_acc,
    const short* __restrict__ h2, const float* __restrict__ cw,
    const int* __restrict__ off, const int* __restrict__ csr,
    const int* __restrict__ ei,
    float* __restrict__ out)
{
    __shared__ short Hs[128][136];

    const int tid = threadIdx.x;
    const int wv = tid >> 6, lane = tid & 63, le = lane & 15, grp = lane >> 4;
    const int nb = blockIdx.x * 128, wbase = wv * 32;
    const int row0 = min(nb + wbase + le, NN - 1);
    const int row1 = min(nb + wbase + 16 + le, NN - 1);

    // aggregation fragments for kc 4..7: cols (kc-4)*32 + grp*8 .. +7
    short8 ag0[4], ag1[4];
    if constexpr (CSR) {
        const int hb = grp * 8;
        {
            float s[32];
            #pragma unroll
            for (int j = 0; j < 32; ++j) s[j] = 0.f;
            const int o = off[row0], c = off[row0 + 1] - o;
            for (int i = 0; i < c; ++i) {
                const int e = csr[o + i];
                const short* hpt = h2 + (size_t)e * 128 + hb;
                #pragma unroll
                for (int q = 0; q < 4; ++q) {
                    const short8 v = *(const short8*)(hpt + q * 32);
                    #pragma unroll
                    for (int j = 0; j < 8; ++j) s[q * 8 + j] += bf2f(v[j]);
                }
            }
            #pragma unroll
            for (int q = 0; q < 4; ++q) {
                short8 r;
                #pragma unroll
                for (int j = 0; j < 8; ++j) r[j] = f2bf(s[q * 8 + j]);
                ag0[q] = r;
            }
        }
        {
            float s[32];
            #pragma unroll
            for (int j = 0; j < 32; ++j) s[j] = 0.f;
            const int o = off[row1], c = off[row1 + 1] - o;
            for (int i = 0; i < c; ++i) {
                const int e = csr[o + i];
                const short* hpt = h2 + (size_t)e * 128 + hb;
                #pragma unroll
                for (int q = 0; q < 4; ++q) {
                    const short8 v = *(const short8*)(hpt + q * 32);
                    #pragma unroll
                    for (int j = 0; j < 8; ++j) s[q * 8 + j] += bf2f(v[j]);
                }
            }
            #pragma unroll
            for (int q = 0; q < 4; ++q) {
                short8 r;
                #pragma unroll
                for (int j = 0; j < 8; ++j) r[j] = f2bf(s[q * 8 + j]);
                ag1[q] = r;
            }
        }
    }

    // MLP1: K=256 ([nf | aggr])
    f32x4 acc[2][8];
    #pragma unroll
    for (int m = 0; m < 2; ++m)
        #pragma unroll
        for (int t = 0; t < 8; ++t) acc[m][t] = (f32x4){0.f, 0.f, 0.f, 0.f};

    const short* w1 = wb + OFF_WN1T;
    #pragma unroll
    for (int kc = 0; kc < 8; ++kc) {
        const int gk = kc * 32 + grp * 8;
        short8 a0, a1;
        if (kc < 4) {
            if (BF16NF) {
                a0 = *(const short8*)&nfb[(size_t)row0 * 128 + gk];
                a1 = *(const short8*)&nfb[(size_t)row1 * 128 + gk];
            } else {
                const float* p0 = nf + (size_t)row0 * 128 + gk;
                const float* p1 = nf + (size_t)row1 * 128 + gk;
                a0 = cvt8(*(const float4*)p0, *(const float4*)(p0 + 4));
                a1 = cvt8(*(const float4*)p1, *(const float4*)(p1 + 4));
            }
        } else if constexpr (CSR) {
            a0 = ag0[kc - 4];
            a1 = ag1[kc - 4];
        } else {
            const float* p0 = aggr + (size_t)row0 * 128 + gk - 128;
            const float* p1 = aggr + (size_t)row1 * 128 + gk - 128;
            a0 = cvt8(*(const float4*)p0, *(const float4*)(p0 + 4));
            a1 = cvt8(*(const float4*)p1, *(const float4*)(p1 + 4));
        }
        short8 bfv[8];
        #pragma unroll
        for (int t = 0; t < 8; ++t)
            bfv[t] = *(const short8*)(w1 + (size_t)(t * 16 + le) * 256 + gk);
        #pragma unroll
        for (int t = 0; t < 8; ++t) {
            acc[0][t] = __builtin_amdgcn_mfma_f32_16x16x32_bf16(a0, bfv[t], acc[0][t], 0, 0, 0);
            acc[1][t] = __builtin_amdgcn_mfma_f32_16x16x32_bf16(a1, bfv[t], acc[1][t], 0, 0, 0);
        }
    }
    #pragma unroll
    for (int t = 0; t < 8; ++t) {
        const float b1 = bn1[t * 16 + le];
        #pragma unroll
        for (int m = 0; m < 2; ++m)
            #pragma unroll
            for (int r = 0; r < 4; ++r)
                Hs[wbase + m * 16 + grp * 4 + r][t * 16 + le] = f2bf(silu_f(acc[m][t][r] + b1));
    }

    // MLP2: K=128, then residual
    f32x4 acc2[2][8];
    #pragma unroll
    for (int m = 0; m < 2; ++m)
        #pragma unroll
        for (int t = 0; t < 8; ++t) acc2[m][t] = (f32x4){0.f, 0.f, 0.f, 0.f};

    const short* w2 = wb + OFF_WN2T;
    #pragma unroll
    for (int kc = 0; kc < 4; ++kc) {
        const int gk = kc * 32 + grp * 8;
        const short8 a0 = *(const short8*)&Hs[wbase + le][gk];
        const short8 a1 = *(const short8*)&Hs[wbase + 16 + le][gk];
        short8 bfv[8];
        #pragma unroll
        for (int t = 0; t < 8; ++t)
            bfv[t] = *(const short8*)(w2 + (size_t)(t * 16 + le) * 128 + gk);
        #pragma unroll
        for (int t = 0; t < 8; ++t) {
            acc2[0][t] = __builtin_amdgcn_mfma_f32_16x16x32_bf16(a0, bfv[t], acc2[0][t], 0, 0, 0);
            acc2[1][t] = __builtin_amdgcn_mfma_f32_16x16x32_bf16(a1, bfv[t], acc2[1][t], 0, 0, 0);
        }
    }
    #pragma unroll
    for (int t = 0; t < 8; ++t) {
        const float b2 = bn2[t * 16 + le];
        #pragma unroll
        for (int m = 0; m < 2; ++m)
            #pragma unroll
            for (int r = 0; r < 4; ++r) {
                const int row = nb + wbase + m * 16 + grp * 4 + r;
                if (row < NN) {
                    const int c = t * 16 + le;
                    out[(size_t)row * 128 + c] = acc2[m][t][r] + b2 + nf[(size_t)row * 128 + c];
                }
            }
    }

    // coords
    if constexpr (CSR) {
        if (tid < 128) {
            const int n = nb + tid;
            if (n < NN) {
                const float cx = coords[3 * n], cy = coords[3 * n + 1], cz = coords[3 * n + 2];
                float ax = 0.f, ay = 0.f, az = 0.f;
                const int o = off[n], c = off[n + 1] - o;
                for (int i = 0; i < c; ++i) {
                    const int e = csr[o + i];
                    const int s = ei[e];
                    const float w = cw[e];
                    const float dx = coords[3 * s] - cx;
                    const float dy = coords[3 * s + 1] - cy;
                    const float dz = coords[3 * s + 2] - cz;
                    const float inv = w / (sqrtf(dx * dx + dy * dy + dz * dz) + 1e-8f);
                    ax += dx * inv; ay += dy * inv; az += dz * inv;
                }
                out[(size_t)NN * 128 + 3 * n + 0] = cx + ax;
                out[(size_t)NN * 128 + 3 * n + 1] = cy + ay;
                out[(size_t)NN * 128 + 3 * n + 2] = cz + az;
            }
        }
    } else {
        for (int i = tid; i < 384; i += 256) {
            const int n = nb + i / 3, j = i % 3;
            if (n < NN)
                out[(size_t)NN * 128 + 3 * n + j] = coords[3 * n + j] + coord_acc[3 * n + j];
        }
    }
}

extern "C" void kernel_launch(void* const* d_in, const int* in_sizes, int n_in,
                              void* d_out, int out_size, void* d_ws, size_t ws_size,
                              hipStream_t stream)
{
    const float* node_feat  = (const float*)d_in[0];
    const float* edge_attr  = (const float*)d_in[1];
    const float* coords     = (const float*)d_in[2];
    const int*   edge_index = (const int*)d_in[3];
    const float* We1 = (const float*)d_in[4];
    const float* be1 = (const float*)d_in[5];
    const float* We2 = (const float*)d_in[6];
    const float* be2 = (const float*)d_in[7];
    const float* Wn1 = (const float*)d_in[8];
    const float* bn1 = (const float*)d_in[9];
    const float* Wn2 = (const float*)d_in[10];
    const float* bn2 = (const float*)d_in[11];
    const float* Wc1 = (const float*)d_in[12];
    const float* bc1 = (const float*)d_in[13];
    const float* Wc2 = (const float*)d_in[14];
    const float* bc2 = (const float*)d_in[15];
    float* out = (float*)d_out;

    const size_t sz_wb  = (size_t)W_TOTAL * 2;
    const size_t sz_nfb = (size_t)NN * 128 * 2;
    const size_t sz_h2  = (size_t)NE * 128 * 2;
    const size_t need_csr = sz_wb + sz_nfb + sz_h2 + (size_t)NE * 4
                          + (size_t)NN * 4 * 3 + 2048 + (size_t)(NN + 1) * 4 + (size_t)NE * 4;
    const size_t need_fb  = sz_wb + sz_nfb + (size_t)NN * 131 * 4;

    const int prep_grid = (W_TOTAL + NFB_ITEMS + NN + 255) / 256;
    const int eg = NE / 128;                 // 3125
    const int ng = (NN + 127) / 128;         // 391
    const int eg256 = (NE + 255) / 256;      // 1563
    const int sg = (NN + 255) / 256;         // 196

    char* p = (char*)d_ws;
    short* wbf = (short*)p; p += sz_wb;

    if (ws_size >= need_csr) {
        short* nfb = (short*)p;  p += sz_nfb;
        short* h2  = (short*)p;  p += sz_h2;
        float* cw  = (float*)p;  p += (size_t)NE * 4;
        int* cnt    = (int*)p;   p += (size_t)NN * 4;
        int* eoff   = (int*)p;   p += (size_t)NN * 4;
        int* bsum   = (int*)p;   p += 1024;
        int* bexcl  = (int*)p;   p += 1024;
        int* off    = (int*)p;   p += (size_t)(NN + 1) * 4;
        int* cursor = (int*)p;   p += (size_t)NN * 4;
        int* csr    = (int*)p;

        prep_all_kernel<<<prep_grid, 256, 0, stream>>>(
            We1, We2, Wn1, Wn2, Wc1, node_feat, wbf, nfb, cnt, 1, 1);

        edge_kernel<true, true><<<eg, 256, 0, stream>>>(
            node_feat, nfb, edge_attr, coords, edge_index, wbf,
            be1, be2, bc1, bc2, Wc2, h2, cw, nullptr, nullptr);

        hist_kernel<<<eg256, 256, 0, stream>>>(edge_index, cnt);
        scanA_kernel<<<sg, 256, 0, stream>>>(cnt, eoff, bsum);
        scanB_kernel<<<1, 256, 0, stream>>>(bsum, bexcl, sg);
        scanC_kernel<<<sg, 256, 0, stream>>>(eoff, bexcl, off, cursor);
        fill_kernel<<<eg256, 256, 0, stream>>>(edge_index, cursor, csr);

        node_kernel<true, true><<<ng, 256, 0, stream>>>(
            node_feat, nfb, coords, wbf, bn1, bn2,
            nullptr, nullptr, h2, cw, off, csr, edge_index, out);
    } else if (ws_size >= need_fb) {
        short* nfb = (short*)p;  p += sz_nfb;
        float* aggr = (float*)p;
        float* coord_acc = aggr + (size_t)NN * 128;

        prep_all_kernel<<<prep_grid, 256, 0, stream>>>(
            We1, We2, Wn1, Wn2, Wc1, node_feat, wbf, nfb, nullptr, 1, 0);
        zero_kernel<<<2048, 256, 0, stream>>>((float4*)aggr, (NN * 128 + NN * 3) / 4);

        edge_kernel<false, true><<<eg, 256, 0, stream>>>(
            node_feat, nfb, edge_attr, coords, edge_index, wbf,
            be1, be2, bc1, bc2, Wc2, nullptr, nullptr, aggr, coord_acc);
        node_kernel<false, true><<<ng, 256, 0, stream>>>(
            node_feat, nfb, coords, wbf, bn1, bn2,
            aggr, coord_acc, nullptr, nullptr, nullptr, nullptr, nullptr, out);
    } else {
        float* aggr = (float*)p;
        float* coord_acc = aggr + (size_t)NN * 128;

        prep_all_kernel<<<prep_grid, 256, 0, stream>>>(
            We1, We2, Wn1, Wn2, Wc1, node_feat, wbf, nullptr, nullptr, 0, 0);
        zero_kernel<<<2048, 256, 0, stream>>>((float4*)aggr, (NN * 128 + NN * 3) / 4);

        edge_kernel<false, false><<<eg, 256, 0, stream>>>(
            node_feat, nullptr, edge_attr, coords, edge_index, wbf,
            be1, be2, bc1, bc2, Wc2, nullptr, nullptr, aggr, coord_acc);
        node_kernel<false, false><<<ng, 256, 0, stream>>>(
            node_feat, nullptr, coords, wbf, bn1, bn2,
            aggr, coord_acc, nullptr, nullptr, nullptr, nullptr, nullptr, out);
    }
}

// Round 6
// 405.119 us; speedup vs baseline: 2.1411x; 1.2788x over previous
//
#include <hip/hip_runtime.h>
#include <hip/hip_bf16.h>
#include <math.h>
#include <stdint.h>

#define NN 50000
#define NE 400000

typedef __attribute__((ext_vector_type(8))) short short8;
typedef __attribute__((ext_vector_type(4))) float f32x4;

// bf16 weight workspace layout (element offsets)
#define OFF_WE1T 0           // [128][320]
#define OFF_WE2T 40960       // [128][128]
#define OFF_WN1T 57344       // [128][256]
#define OFF_WN2T 90112       // [128][128]
#define OFF_WC1T 106496      // [64][128]
#define W_TOTAL  114688

#define NFB_ITEMS 800000     // NN*128/8
#define EAB_ITEMS 3200000    // NE*64/8

__device__ __forceinline__ float silu_f(float x) {
    return x * (1.0f / (1.0f + __expf(-x)));
}
__device__ __forceinline__ short f2bf(float f) {
    __hip_bfloat16 b = __float2bfloat16(f);
    return *reinterpret_cast<short*>(&b);
}
__device__ __forceinline__ short8 cvt8(float4 a, float4 b) {
    short8 r;
    r[0] = f2bf(a.x); r[1] = f2bf(a.y); r[2] = f2bf(a.z); r[3] = f2bf(a.w);
    r[4] = f2bf(b.x); r[5] = f2bf(b.y); r[6] = f2bf(b.z); r[7] = f2bf(b.w);
    return r;
}

// async global->LDS, 16B per lane; LDS dest = (wave-uniform base) + lane*16
__device__ __forceinline__ void gload16(const short* g, short* l) {
    __builtin_amdgcn_global_load_lds(
        (const __attribute__((address_space(1))) void*)g,
        (__attribute__((address_space(3))) void*)l, 16, 0, 0);
}

// ---------------- zero aggr/coord accumulators ----------------
__global__ void zero_kernel(float4* __restrict__ p, int n4) {
    int i = blockIdx.x * blockDim.x + threadIdx.x;
    int st = gridDim.x * blockDim.x;
    for (; i < n4; i += st) p[i] = make_float4(0.f, 0.f, 0.f, 0.f);
}

// ---------------- prep: weights fp32[K][N] -> bf16[N][K]; nf,ea -> bf16 ----------------
__global__ __launch_bounds__(256) void prep_kernel(
    const float* __restrict__ We1, const float* __restrict__ We2,
    const float* __restrict__ Wn1, const float* __restrict__ Wn2,
    const float* __restrict__ Wc1, const float* __restrict__ nf,
    const float* __restrict__ ea,
    short* __restrict__ wb, short* __restrict__ nfb, short* __restrict__ eab,
    int full)
{
    const int i = blockIdx.x * 256 + threadIdx.x;
    if (i < W_TOTAL) {
        const float* src; int N, n, k, rel;
        if (i < OFF_WE2T)      { rel = i;            src = We1; N = 128; n = rel / 320; k = rel % 320; }
        else if (i < OFF_WN1T) { rel = i - OFF_WE2T; src = We2; N = 128; n = rel / 128; k = rel % 128; }
        else if (i < OFF_WN2T) { rel = i - OFF_WN1T; src = Wn1; N = 128; n = rel / 256; k = rel % 256; }
        else if (i < OFF_WC1T) { rel = i - OFF_WN2T; src = Wn2; N = 128; n = rel / 128; k = rel % 128; }
        else                   { rel = i - OFF_WC1T; src = Wc1; N = 64;  n = rel / 128; k = rel % 128; }
        wb[i] = f2bf(src[(size_t)k * N + n]);
    } else if (full && i < W_TOTAL + NFB_ITEMS) {
        const int j = i - W_TOTAL;
        const float4 a = *(const float4*)&nf[(size_t)j * 8];
        const float4 b = *(const float4*)&nf[(size_t)j * 8 + 4];
        *(short8*)&nfb[(size_t)j * 8] = cvt8(a, b);
    } else if (full && i < W_TOTAL + NFB_ITEMS + EAB_ITEMS) {
        const int j = i - W_TOTAL - NFB_ITEMS;
        const float4 a = *(const float4*)&ea[(size_t)j * 8];
        const float4 b = *(const float4*)&ea[(size_t)j * 8 + 4];
        *(short8*)&eab[(size_t)j * 8] = cvt8(a, b);
    }
}

// ---------------- edge pipeline: gload_lds-staged gathers, MFMA, barrier-free ----------------
// 128 edges/block, 4 waves, 32 edges/wave. Per-wave 16KB LDS: A-stage (fragment
// layout, written by global_load_lds) reused as Hs for h1/h2. All 16 gather
// staging ops issue up-front with zero VGPR cost -> latencies overlap.
template<bool STAGED>
__global__ __launch_bounds__(256, 2) void edge_kernel(
    const float* __restrict__ nf, const short* __restrict__ nfb,
    const float* __restrict__ ea, const short* __restrict__ eab,
    const float* __restrict__ coords, const int* __restrict__ ei,
    const short* __restrict__ wb,
    const float* __restrict__ be1, const float* __restrict__ be2,
    const float* __restrict__ bc1, const float* __restrict__ bc2,
    const float* __restrict__ Wc2f,
    float* __restrict__ aggr, float* __restrict__ coord_acc)
{
    __shared__ short smem[4][8192];   // 16KB/wave

    const int tid = threadIdx.x;
    const int wv = tid >> 6, lane = tid & 63, le = lane & 15, g = lane >> 4;
    const int base = (blockIdx.x * 4 + wv) * 32;
    short* stage = smem[wv];
    short (*Hs)[136] = (short(*)[136])stage;

    const int s0 = ei[base + le],      s1 = ei[base + 16 + le];
    const int d0 = ei[NE + base + le], d1 = ei[NE + base + 16 + le];

    short8 ea8[2][2];
    if constexpr (STAGED) {
        // stage all 16 gathered nf chunks (src kc 0..3, dst kc 4..7) x 2 halves
        #pragma unroll
        for (int kc = 0; kc < 8; ++kc) {
            const int r0 = (kc < 4) ? s0 : d0;
            const int r1 = (kc < 4) ? s1 : d1;
            const int col = (kc & 3) * 32 + g * 8;
            gload16(nfb + (size_t)r0 * 128 + col, stage + (kc * 2 + 0) * 512);
            gload16(nfb + (size_t)r1 * 128 + col, stage + (kc * 2 + 1) * 512);
        }
        // edge_attr chunks (coalesced) to registers
        #pragma unroll
        for (int q = 0; q < 2; ++q) {
            ea8[0][q] = *(const short8*)&eab[(size_t)(base + le) * 64 + q * 32 + g * 8];
            ea8[1][q] = *(const short8*)&eab[(size_t)(base + 16 + le) * 64 + q * 32 + g * 8];
        }
        asm volatile("s_waitcnt vmcnt(0)" ::: "memory");
        __builtin_amdgcn_sched_barrier(0);
    }

    // ===== MLP1: h1 = silu(A @ We1 + be1), K=320, N=128
    f32x4 acc[2][8];
    #pragma unroll
    for (int m = 0; m < 2; ++m)
        #pragma unroll
        for (int t = 0; t < 8; ++t) acc[m][t] = (f32x4){0.f, 0.f, 0.f, 0.f};

    const short* w1 = wb + OFF_WE1T;
    #pragma unroll
    for (int kc = 0; kc < 10; ++kc) {
        const int gk = kc * 32 + g * 8;
        short8 a0, a1;
        if (kc < 8) {
            if constexpr (STAGED) {
                a0 = *(const short8*)&stage[(kc * 2 + 0) * 512 + lane * 8];
                a1 = *(const short8*)&stage[(kc * 2 + 1) * 512 + lane * 8];
            } else {
                const int r0 = (kc < 4) ? s0 : d0;
                const int r1 = (kc < 4) ? s1 : d1;
                const int col = (kc & 3) * 32 + g * 8;
                const float* p0 = nf + (size_t)r0 * 128 + col;
                const float* p1 = nf + (size_t)r1 * 128 + col;
                a0 = cvt8(*(const float4*)p0, *(const float4*)(p0 + 4));
                a1 = cvt8(*(const float4*)p1, *(const float4*)(p1 + 4));
            }
        } else {
            if constexpr (STAGED) {
                a0 = ea8[0][kc - 8];
                a1 = ea8[1][kc - 8];
            } else {
                const float* p0 = ea + (size_t)(base + le) * 64 + (kc - 8) * 32 + g * 8;
                const float* p1 = ea + (size_t)(base + 16 + le) * 64 + (kc - 8) * 32 + g * 8;
                a0 = cvt8(*(const float4*)p0, *(const float4*)(p0 + 4));
                a1 = cvt8(*(const float4*)p1, *(const float4*)(p1 + 4));
            }
        }
        short8 bfv[8];
        #pragma unroll
        for (int t = 0; t < 8; ++t)
            bfv[t] = *(const short8*)(w1 + (size_t)(t * 16 + le) * 320 + gk);
        #pragma unroll
        for (int t = 0; t < 8; ++t) {
            acc[0][t] = __builtin_amdgcn_mfma_f32_16x16x32_bf16(a0, bfv[t], acc[0][t], 0, 0, 0);
            acc[1][t] = __builtin_amdgcn_mfma_f32_16x16x32_bf16(a1, bfv[t], acc[1][t], 0, 0, 0);
        }
    }

    // h1 epilogue -> Hs (reuses stage; safe: writes depend on all staged reads)
    #pragma unroll
    for (int t = 0; t < 8; ++t) {
        const float b1 = be1[t * 16 + le];
        #pragma unroll
        for (int m = 0; m < 2; ++m)
            #pragma unroll
            for (int r = 0; r < 4; ++r)
                Hs[m * 16 + g * 4 + r][t * 16 + le] = f2bf(silu_f(acc[m][t][r] + b1));
    }

    // ===== MLP2: h2 = silu(h1 @ We2 + be2), K=128
    f32x4 acc2[2][8];
    #pragma unroll
    for (int m = 0; m < 2; ++m)
        #pragma unroll
        for (int t = 0; t < 8; ++t) acc2[m][t] = (f32x4){0.f, 0.f, 0.f, 0.f};

    const short* w2 = wb + OFF_WE2T;
    #pragma unroll
    for (int kc = 0; kc < 4; ++kc) {
        const int gk = kc * 32 + g * 8;
        const short8 a0 = *(const short8*)&Hs[le][gk];
        const short8 a1 = *(const short8*)&Hs[16 + le][gk];
        short8 bfv[8];
        #pragma unroll
        for (int t = 0; t < 8; ++t)
            bfv[t] = *(const short8*)(w2 + (size_t)(t * 16 + le) * 128 + gk);
        #pragma unroll
        for (int t = 0; t < 8; ++t) {
            acc2[0][t] = __builtin_amdgcn_mfma_f32_16x16x32_bf16(a0, bfv[t], acc2[0][t], 0, 0, 0);
            acc2[1][t] = __builtin_amdgcn_mfma_f32_16x16x32_bf16(a1, bfv[t], acc2[1][t], 0, 0, 0);
        }
    }

    // h2 epilogue: quarter-wave contiguous atomics (round-3 proven) + Hs overwrite
    int dstv[2][4];
    #pragma unroll
    for (int r = 0; r < 4; ++r) {
        dstv[0][r] = __shfl(d0, g * 4 + r);
        dstv[1][r] = __shfl(d1, g * 4 + r);
    }
    #pragma unroll
    for (int t = 0; t < 8; ++t) {
        const float b2 = be2[t * 16 + le];
        #pragma unroll
        for (int m = 0; m < 2; ++m)
            #pragma unroll
            for (int r = 0; r < 4; ++r) {
                const float v = silu_f(acc2[m][t][r] + b2);
                atomicAdd(&aggr[(size_t)dstv[m][r] * 128 + t * 16 + le], v);
                Hs[m * 16 + g * 4 + r][t * 16 + le] = f2bf(v);
            }
    }

    // ===== coord MLP: c1 = silu(h2 @ Wc1 + bc1), K=128, N=64
    f32x4 acc3[2][4];
    #pragma unroll
    for (int m = 0; m < 2; ++m)
        #pragma unroll
        for (int t = 0; t < 4; ++t) acc3[m][t] = (f32x4){0.f, 0.f, 0.f, 0.f};

    const short* wc = wb + OFF_WC1T;
    #pragma unroll
    for (int kc = 0; kc < 4; ++kc) {
        const int gk = kc * 32 + g * 8;
        const short8 a0 = *(const short8*)&Hs[le][gk];
        const short8 a1 = *(const short8*)&Hs[16 + le][gk];
        short8 bfv[4];
        #pragma unroll
        for (int t = 0; t < 4; ++t)
            bfv[t] = *(const short8*)(wc + (size_t)(t * 16 + le) * 128 + gk);
        #pragma unroll
        for (int t = 0; t < 4; ++t) {
            acc3[0][t] = __builtin_amdgcn_mfma_f32_16x16x32_bf16(a0, bfv[t], acc3[0][t], 0, 0, 0);
            acc3[1][t] = __builtin_amdgcn_mfma_f32_16x16x32_bf16(a1, bfv[t], acc3[1][t], 0, 0, 0);
        }
    }

    // coord_w partials + butterfly over le lanes
    float part[2][4];
    #pragma unroll
    for (int m = 0; m < 2; ++m)
        #pragma unroll
        for (int r = 0; r < 4; ++r) part[m][r] = 0.f;
    #pragma unroll
    for (int t = 0; t < 4; ++t) {
        const float bc = bc1[t * 16 + le];
        const float w2c = Wc2f[t * 16 + le];
        #pragma unroll
        for (int m = 0; m < 2; ++m)
            #pragma unroll
            for (int r = 0; r < 4; ++r)
                part[m][r] += silu_f(acc3[m][t][r] + bc) * w2c;
    }
    #pragma unroll
    for (int mask = 1; mask <= 8; mask <<= 1)
        #pragma unroll
        for (int m = 0; m < 2; ++m)
            #pragma unroll
            for (int r = 0; r < 4; ++r)
                part[m][r] += __shfl_xor(part[m][r], mask);

    // src/dst for owner lanes, computed pre-branch (all lanes active for shfl)
    const int rr = le & 3;
    const int sA = __shfl(s0, g * 4 + rr), sB = __shfl(s1, g * 4 + rr);
    const int dA = __shfl(d0, g * 4 + rr), dB = __shfl(d1, g * 4 + rr);

    if (le < 8) {
        const int m = le >> 2, r = le & 3;
        float v;
        if (m == 0) v = (r == 0) ? part[0][0] : (r == 1) ? part[0][1] : (r == 2) ? part[0][2] : part[0][3];
        else        v = (r == 0) ? part[1][0] : (r == 1) ? part[1][1] : (r == 2) ? part[1][2] : part[1][3];
        const int s = m ? sB : sA, d = m ? dB : dA;
        const float dx = coords[3 * s + 0] - coords[3 * d + 0];
        const float dy = coords[3 * s + 1] - coords[3 * d + 1];
        const float dz = coords[3 * s + 2] - coords[3 * d + 2];
        const float wq = v + bc2[0];
        const float inv = wq / (sqrtf(dx * dx + dy * dy + dz * dz) + 1e-8f);
        atomicAdd(&coord_acc[3 * d + 0], dx * inv);
        atomicAdd(&coord_acc[3 * d + 1], dy * inv);
        atomicAdd(&coord_acc[3 * d + 2], dz * inv);
    }
}

// ---------------- node update (MFMA, barrier-free) ----------------
template<bool BF16NF>
__global__ __launch_bounds__(256, 2) void node_kernel(
    const float* __restrict__ nf, const short* __restrict__ nfb,
    const float* __restrict__ coords, const short* __restrict__ wb,
    const float* __restrict__ bn1, const float* __restrict__ bn2,
    const float* __restrict__ aggr, const float* __restrict__ coord_acc,
    float* __restrict__ out)
{
    __shared__ short Hs[128][136];

    const int tid = threadIdx.x;
    const int wv = tid >> 6, lane = tid & 63, le = lane & 15, grp = lane >> 4;
    const int nb = blockIdx.x * 128, wbase = wv * 32;
    const int row0 = min(nb + wbase + le, NN - 1);
    const int row1 = min(nb + wbase + 16 + le, NN - 1);

    // MLP1: K=256 ([nf | aggr])
    f32x4 acc[2][8];
    #pragma unroll
    for (int m = 0; m < 2; ++m)
        #pragma unroll
        for (int t = 0; t < 8; ++t) acc[m][t] = (f32x4){0.f, 0.f, 0.f, 0.f};

    const short* w1 = wb + OFF_WN1T;
    #pragma unroll
    for (int kc = 0; kc < 8; ++kc) {
        const int gk = kc * 32 + grp * 8;
        short8 a0, a1;
        if (kc < 4) {
            if (BF16NF) {
                a0 = *(const short8*)&nfb[(size_t)row0 * 128 + gk];
                a1 = *(const short8*)&nfb[(size_t)row1 * 128 + gk];
            } else {
                const float* p0 = nf + (size_t)row0 * 128 + gk;
                const float* p1 = nf + (size_t)row1 * 128 + gk;
                a0 = cvt8(*(const float4*)p0, *(const float4*)(p0 + 4));
                a1 = cvt8(*(const float4*)p1, *(const float4*)(p1 + 4));
            }
        } else {
            const float* p0 = aggr + (size_t)row0 * 128 + gk - 128;
            const float* p1 = aggr + (size_t)row1 * 128 + gk - 128;
            a0 = cvt8(*(const float4*)p0, *(const float4*)(p0 + 4));
            a1 = cvt8(*(const float4*)p1, *(const float4*)(p1 + 4));
        }
        short8 bfv[8];
        #pragma unroll
        for (int t = 0; t < 8; ++t)
            bfv[t] = *(const short8*)(w1 + (size_t)(t * 16 + le) * 256 + gk);
        #pragma unroll
        for (int t = 0; t < 8; ++t) {
            acc[0][t] = __builtin_amdgcn_mfma_f32_16x16x32_bf16(a0, bfv[t], acc[0][t], 0, 0, 0);
            acc[1][t] = __builtin_amdgcn_mfma_f32_16x16x32_bf16(a1, bfv[t], acc[1][t], 0, 0, 0);
        }
    }
    #pragma unroll
    for (int t = 0; t < 8; ++t) {
        const float b1 = bn1[t * 16 + le];
        #pragma unroll
        for (int m = 0; m < 2; ++m)
            #pragma unroll
            for (int r = 0; r < 4; ++r)
                Hs[wbase + m * 16 + grp * 4 + r][t * 16 + le] = f2bf(silu_f(acc[m][t][r] + b1));
    }

    // MLP2: K=128, then residual
    f32x4 acc2[2][8];
    #pragma unroll
    for (int m = 0; m < 2; ++m)
        #pragma unroll
        for (int t = 0; t < 8; ++t) acc2[m][t] = (f32x4){0.f, 0.f, 0.f, 0.f};

    const short* w2 = wb + OFF_WN2T;
    #pragma unroll
    for (int kc = 0; kc < 4; ++kc) {
        const int gk = kc * 32 + grp * 8;
        const short8 a0 = *(const short8*)&Hs[wbase + le][gk];
        const short8 a1 = *(const short8*)&Hs[wbase + 16 + le][gk];
        short8 bfv[8];
        #pragma unroll
        for (int t = 0; t < 8; ++t)
            bfv[t] = *(const short8*)(w2 + (size_t)(t * 16 + le) * 128 + gk);
        #pragma unroll
        for (int t = 0; t < 8; ++t) {
            acc2[0][t] = __builtin_amdgcn_mfma_f32_16x16x32_bf16(a0, bfv[t], acc2[0][t], 0, 0, 0);
            acc2[1][t] = __builtin_amdgcn_mfma_f32_16x16x32_bf16(a1, bfv[t], acc2[1][t], 0, 0, 0);
        }
    }
    #pragma unroll
    for (int t = 0; t < 8; ++t) {
        const float b2 = bn2[t * 16 + le];
        #pragma unroll
        for (int m = 0; m < 2; ++m)
            #pragma unroll
            for (int r = 0; r < 4; ++r) {
                const int row = nb + wbase + m * 16 + grp * 4 + r;
                if (row < NN) {
                    const int c = t * 16 + le;
                    out[(size_t)row * 128 + c] = acc2[m][t][r] + b2 + nf[(size_t)row * 128 + c];
                }
            }
    }

    // coords epilogue
    for (int i = tid; i < 384; i += 256) {
        const int n = nb + i / 3, j = i % 3;
        if (n < NN)
            out[(size_t)NN * 128 + 3 * n + j] = coords[3 * n + j] + coord_acc[3 * n + j];
    }
}

extern "C" void kernel_launch(void* const* d_in, const int* in_sizes, int n_in,
                              void* d_out, int out_size, void* d_ws, size_t ws_size,
                              hipStream_t stream)
{
    const float* node_feat  = (const float*)d_in[0];
    const float* edge_attr  = (const float*)d_in[1];
    const float* coords     = (const float*)d_in[2];
    const int*   edge_index = (const int*)d_in[3];
    const float* We1 = (const float*)d_in[4];
    const float* be1 = (const float*)d_in[5];
    const float* We2 = (const float*)d_in[6];
    const float* be2 = (const float*)d_in[7];
    const float* Wn1 = (const float*)d_in[8];
    const float* bn1 = (const float*)d_in[9];
    const float* Wn2 = (const float*)d_in[10];
    const float* bn2 = (const float*)d_in[11];
    const float* Wc1 = (const float*)d_in[12];
    const float* bc1 = (const float*)d_in[13];
    const float* Wc2 = (const float*)d_in[14];
    const float* bc2 = (const float*)d_in[15];
    float* out = (float*)d_out;

    const size_t sz_wb   = (size_t)W_TOTAL * 2;            // 229 KB
    const size_t sz_agg  = (size_t)NN * 128 * 4;           // 25.6 MB
    const size_t sz_cac  = (size_t)NN * 3 * 4;             // 600 KB
    const size_t sz_nfb  = (size_t)NN * 128 * 2;           // 12.8 MB
    const size_t sz_eab  = (size_t)NE * 64 * 2;            // 51.2 MB
    const size_t need_full = sz_wb + sz_agg + sz_cac + sz_nfb + sz_eab;   // ~90.4 MB
    const size_t need_min  = sz_wb + sz_agg + sz_cac;                     // ~26.4 MB

    char* p = (char*)d_ws;
    short* wbf       = (short*)p;  p += sz_wb;
    float* aggr      = (float*)p;  p += sz_agg;
    float* coord_acc = (float*)p;  p += sz_cac;
    short* nfb       = (short*)p;  p += sz_nfb;
    short* eab       = (short*)p;

    const int n4 = (NN * 128 + NN * 3) / 4;   // re-zero accumulators every call
    const int eg = NE / 128;                  // 3125
    const int ng = (NN + 127) / 128;          // 391

    if (ws_size >= need_full) {
        const int pg = (W_TOTAL + NFB_ITEMS + EAB_ITEMS + 255) / 256;
        prep_kernel<<<pg, 256, 0, stream>>>(
            We1, We2, Wn1, Wn2, Wc1, node_feat, edge_attr, wbf, nfb, eab, 1);
        zero_kernel<<<2048, 256, 0, stream>>>((float4*)aggr, n4);

        edge_kernel<true><<<eg, 256, 0, stream>>>(
            node_feat, nfb, edge_attr, eab, coords, edge_index, wbf,
            be1, be2, bc1, bc2, Wc2, aggr, coord_acc);

        node_kernel<true><<<ng, 256, 0, stream>>>(
            node_feat, nfb, coords, wbf, bn1, bn2, aggr, coord_acc, out);
    } else {
        const int pg = (W_TOTAL + 255) / 256;
        prep_kernel<<<pg, 256, 0, stream>>>(
            We1, We2, Wn1, Wn2, Wc1, node_feat, edge_attr, wbf, nullptr, nullptr, 0);
        zero_kernel<<<2048, 256, 0, stream>>>((float4*)aggr, n4);

        edge_kernel<false><<<eg, 256, 0, stream>>>(
            node_feat, nullptr, edge_attr, nullptr, coords, edge_index, wbf,
            be1, be2, bc1, bc2, Wc2, aggr, coord_acc);

        node_kernel<false><<<ng, 256, 0, stream>>>(
            node_feat, nullptr, coords, wbf, bn1, bn2, aggr, coord_acc, out);
    }
}